// Round 1
// baseline (73.475 us; speedup 1.0000x reference)
//
#include <hip/hip_runtime.h>
#include <hip/hip_bf16.h>

// Fused:  t4[o,n,m,i] = sum_{j,k} a[o,j,n,m+k-3] * W1[j,k,i]
//         t5[o,p,n,m] = sum_i t4[o,n,m,i] * W0[p,i]
//         out[0, o*48+p, (n+1)%56, m] = t5[o,p,n,m]       (roll +1 on axis 2)
//
// One block per (o, n) source row: grid = 2*56 = 112 blocks, 64 threads (1 wave).
// LDS: padded input row (12x62), W1 (756), W0 (432), t4 tile (56x9). ~9.7 KB.

__global__ __launch_bounds__(64) void fused_shiftconv_kernel(
    const float* __restrict__ x,    // (24,56,56) viewed as a(2,12,56,56)
    const float* __restrict__ W0,   // (48,9)
    const float* __restrict__ W1,   // (12,7,9)
    float* __restrict__ out)        // (96,56,56)
{
    __shared__ float sA[12][62];    // padded row: sA[j][mm] = a[o,j,n,mm-3] (0 in pads)
    __shared__ float sW1[756];      // [j*7*9 + k*9 + i]
    __shared__ float sW0[432];      // [p*9 + i]
    __shared__ float sT4[56][9];

    const int tid = threadIdx.x;
    const int o = blockIdx.x / 56;
    const int n = blockIdx.x % 56;

    // --- stage weights ---
    for (int idx = tid; idx < 756; idx += 64) sW1[idx] = W1[idx];
    for (int idx = tid; idx < 432; idx += 64) sW0[idx] = W0[idx];

    // --- stage padded input row for this (o, n) ---
    for (int idx = tid; idx < 12 * 62; idx += 64) {
        const int j  = idx / 62;
        const int mm = idx % 62;
        const int msrc = mm - 3;
        float v = 0.0f;
        if (msrc >= 0 && msrc < 56)
            v = x[((o * 12 + j) * 56 + n) * 56 + msrc];
        sA[j][mm] = v;
    }
    __syncthreads();

    // --- phase 1: t4[m][i], one m per lane (56 of 64 lanes active) ---
    if (tid < 56) {
        const int m = tid;
        float acc[9];
#pragma unroll
        for (int i = 0; i < 9; ++i) acc[i] = 0.0f;

        for (int j = 0; j < 12; ++j) {
#pragma unroll
            for (int k = 0; k < 7; ++k) {
                const float v = sA[j][m + k];            // stride-1 across lanes
                const float* w = &sW1[(j * 7 + k) * 9];  // wave-uniform broadcast
#pragma unroll
                for (int i = 0; i < 9; ++i) acc[i] += v * w[i];
            }
        }
#pragma unroll
        for (int i = 0; i < 9; ++i) sT4[m][i] = acc[i];
    }
    __syncthreads();

    // --- phase 2: 48*56 outputs, roll +1 along n ---
    const int n_out = (n + 1) % 56;
    for (int idx2 = tid; idx2 < 48 * 56; idx2 += 64) {
        const int p = idx2 / 56;
        const int m = idx2 % 56;
        const float* w = &sW0[p * 9];
        const float* t = &sT4[m][0];                     // stride-9: 9 coprime 32, no conflicts
        float acc = 0.0f;
#pragma unroll
        for (int i = 0; i < 9; ++i) acc += w[i] * t[i];
        out[((o * 48 + p) * 56 + n_out) * 56 + m] = acc;
    }
}

extern "C" void kernel_launch(void* const* d_in, const int* in_sizes, int n_in,
                              void* d_out, int out_size, void* d_ws, size_t ws_size,
                              hipStream_t stream) {
    const float* x  = (const float*)d_in[0];
    const float* W0 = (const float*)d_in[1];
    const float* W1 = (const float*)d_in[2];
    float* out = (float*)d_out;

    fused_shiftconv_kernel<<<dim3(112), dim3(64), 0, stream>>>(x, W0, W1, out);
}

// Round 2
// 61.002 us; speedup vs baseline: 1.2045x; 1.2045x over previous
//
#include <hip/hip_runtime.h>
#include <hip/hip_bf16.h>

// Fused:  t4[o,n,m,i] = sum_{j,k} a[o,j,n,m+k-3] * W1[j,k,i]
//         out[0, o*48+p, (n+1)%56, m] = sum_i t4[o,n,m,i] * W0[p,i]
//
// One block per (o, n) source row: grid = 112, 256 threads (4 waves).
// Phase 1 splits j across waves (3 each) into LDS partials; phase 1b reduces
// into a TRANSPOSED t4 (sT4t[9][60]) so phase 2 can use ds_read_b128 +
// global_store_dwordx4 (row bases are 224 B-aligned, m0 % 4 == 0).

__global__ __launch_bounds__(256) void fused_shiftconv_v2(
    const float* __restrict__ x,    // (24,56,56) viewed as a(2,12,56,56)
    const float* __restrict__ W0,   // (48,9)
    const float* __restrict__ W1,   // (12,7,9)
    float* __restrict__ out)        // (96,56,56)
{
    __shared__ __align__(16) float sA[12][64];      // padded row, sA[j][m+3] = a[o,j,n,m]
    __shared__ __align__(16) float sW1[756];        // [j*63 + k*9 + i]
    __shared__ __align__(16) float sW0[432];        // [p*9 + i]
    __shared__ __align__(16) float sPart[4][9][60]; // per-wave j-partials, transposed
    __shared__ __align__(16) float sT4t[9][60];     // t4 transposed: [i][m]

    const int tid = threadIdx.x;
    const int o = blockIdx.x / 56;
    const int n = blockIdx.x % 56;

    // --- stage weights (float4: 756/4=189, 432/4=108) ---
    {
        const float4* W1v = (const float4*)W1;
        float4* s1 = (float4*)sW1;
        for (int idx = tid; idx < 189; idx += 256) s1[idx] = W1v[idx];
        const float4* W0v = (const float4*)W0;
        float4* s0 = (float4*)sW0;
        for (int idx = tid; idx < 108; idx += 256) s0[idx] = W0v[idx];
    }

    // --- stage padded input row (744 useful elements; pads zeroed) ---
    for (int idx = tid; idx < 12 * 64; idx += 256) {
        const int j = idx >> 6, mm = idx & 63;
        const int ms = mm - 3;
        float v = 0.0f;
        if (ms >= 0 && ms < 56)
            v = x[((o * 12 + j) * 56 + n) * 56 + ms];
        sA[j][mm] = v;
    }
    __syncthreads();

    // --- phase 1: wave w accumulates j = 3w..3w+2 (lanes 0..55 = m) ---
    {
        const int wave = tid >> 6, lane = tid & 63;
        if (lane < 56) {
            const int m = lane;
            float acc[9];
#pragma unroll
            for (int i = 0; i < 9; ++i) acc[i] = 0.0f;
#pragma unroll
            for (int jj = 0; jj < 3; ++jj) {
                const int j = wave * 3 + jj;
#pragma unroll
                for (int k = 0; k < 7; ++k) {
                    const float v = sA[j][m + k];            // stride-1 lanes
                    const float* w = &sW1[(j * 7 + k) * 9];  // wave-uniform bcast
#pragma unroll
                    for (int i = 0; i < 9; ++i) acc[i] += v * w[i];
                }
            }
#pragma unroll
            for (int i = 0; i < 9; ++i) sPart[wave][i][m] = acc[i];
        }
    }
    __syncthreads();

    // --- phase 1b: reduce 4 partials into transposed t4 ---
    for (int idx = tid; idx < 504; idx += 256) {
        const int i = idx / 56, m = idx % 56;
        sT4t[i][m] = sPart[0][i][m] + sPart[1][i][m]
                   + sPart[2][i][m] + sPart[3][i][m];
    }
    __syncthreads();

    // --- phase 2: 48x56 outputs as 672 float4 (roll +1 along n) ---
    const int n_out = (n + 1) % 56;
    for (int v4 = tid; v4 < 672; v4 += 256) {
        const int p = v4 / 14;
        const int m0 = (v4 % 14) * 4;
        const float* w = &sW0[p * 9];
        float4 acc = {0.0f, 0.0f, 0.0f, 0.0f};
#pragma unroll
        for (int i = 0; i < 9; ++i) {
            const float4 t = *(const float4*)&sT4t[i][m0];  // ds_read_b128
            const float wi = w[i];
            acc.x += wi * t.x; acc.y += wi * t.y;
            acc.z += wi * t.z; acc.w += wi * t.w;
        }
        *(float4*)&out[((o * 48 + p) * 56 + n_out) * 56 + m0] = acc;
    }
}

extern "C" void kernel_launch(void* const* d_in, const int* in_sizes, int n_in,
                              void* d_out, int out_size, void* d_ws, size_t ws_size,
                              hipStream_t stream) {
    const float* x  = (const float*)d_in[0];
    const float* W0 = (const float*)d_in[1];
    const float* W1 = (const float*)d_in[2];
    float* out = (float*)d_out;

    fused_shiftconv_v2<<<dim3(112), dim3(256), 0, stream>>>(x, W0, W1, out);
}